// Round 1
// baseline (745.703 us; speedup 1.0000x reference)
//
#include <hip/hip_runtime.h>

typedef __bf16 bf16x8 __attribute__((ext_vector_type(8)));
typedef float  f32x4  __attribute__((ext_vector_type(4)));
typedef unsigned short u16;

#define LOG2E    1.4426950408889634f
#define SM_SCALE 0.08838834764831845f   // 1/sqrt(128)

__device__ __forceinline__ u16 f2bf(float f) {
    unsigned int u = __builtin_bit_cast(unsigned int, f);
    u += 0x7fffu + ((u >> 16) & 1u);    // RNE
    return (u16)(u >> 16);
}
__device__ __forceinline__ float b2f(u16 h) {
    unsigned int u = ((unsigned int)h) << 16;
    return __builtin_bit_cast(float, u);
}
__device__ __forceinline__ void glds16(const void* g, void* l) {
    __builtin_amdgcn_global_load_lds(
        (__attribute__((address_space(1))) void*)g,
        (__attribute__((address_space(3))) void*)l, 16, 0, 0);
}

// ---------------- fp32 -> bf16 convert ----------------
__global__ void cvt_bf16_k(const float* __restrict__ in, u16* __restrict__ out, size_t n4) {
    size_t i = (size_t)blockIdx.x * blockDim.x + threadIdx.x;
    size_t stride = (size_t)gridDim.x * blockDim.x;
    for (; i < n4; i += stride) {
        float4 v = ((const float4*)in)[i];
        ushort4 r;
        r.x = f2bf(v.x); r.y = f2bf(v.y); r.z = f2bf(v.z); r.w = f2bf(v.w);
        ((ushort4*)out)[i] = r;
    }
}

// ---------------- W (K x N fp32) -> WT (N x K bf16) ----------------
__global__ void transpose_w_k(const float* __restrict__ W, u16* __restrict__ WT, int K, int N) {
    __shared__ float tile[32][33];
    int tx = threadIdx.x & 31, ty = threadIdx.x >> 5;   // 256 threads: ty 0..7
    int bx = blockIdx.x, by = blockIdx.y;               // bx: N/32, by: K/32
    #pragma unroll
    for (int i = 0; i < 4; ++i) {
        int r = by*32 + ty + i*8;
        tile[ty + i*8][tx] = W[(size_t)r * N + bx*32 + tx];
    }
    __syncthreads();
    #pragma unroll
    for (int i = 0; i < 4; ++i) {
        int n = bx*32 + ty + i*8;
        WT[(size_t)n * K + by*32 + tx] = f2bf(tile[tx][ty + i*8]);
    }
}

// ---------------- v (B,T,H*128) bf16 -> vt (B,H,128,T) bf16 ----------------
__global__ void transpose_v_k(const u16* __restrict__ V, u16* __restrict__ VT) {
    __shared__ u16 tile[32][33];
    int tx = threadIdx.x & 31, ty = threadIdx.x >> 5;
    int tT = blockIdx.x, tD = blockIdx.y, bh = blockIdx.z;
    int b = bh >> 4, h = bh & 15;
    #pragma unroll
    for (int i = 0; i < 4; ++i) {
        int t = tT*32 + ty + i*8;
        int d = tD*32 + tx;
        tile[ty + i*8][tx] = V[((size_t)(b*2048 + t))*2048 + h*128 + d];
    }
    __syncthreads();
    #pragma unroll
    for (int i = 0; i < 4; ++i) {
        int d = tD*32 + ty + i*8;
        int t = tT*32 + tx;
        VT[((size_t)bh*128 + d)*2048 + t] = tile[tx][ty + i*8];
    }
}

// ---------------- RoPE in-place on (B,T,16,128) bf16 ----------------
__global__ void rope_k(u16* __restrict__ X, const float* __restrict__ C, const float* __restrict__ S) {
    size_t idx = (size_t)blockIdx.x * blockDim.x + threadIdx.x;  // one thread = 4 pairs (8 elems)
    size_t pair0 = idx * 4;
    int i = (int)(pair0 & 63);            // pair index within head row (0..63), multiple of 4
    size_t rem = pair0 >> 6;              // (b*T + t)*16 + h
    int t = (int)((rem >> 4) & 2047);     // /H % T
    float4 cv = *(const float4*)(C + (size_t)t*64 + i);
    float4 sv = *(const float4*)(S + (size_t)t*64 + i);
    ushort4 lo = ((const ushort4*)X)[idx*2];
    ushort4 hi = ((const ushort4*)X)[idx*2 + 1];
    float e0 = b2f(lo.x), o0 = b2f(lo.y), e1 = b2f(lo.z), o1 = b2f(lo.w);
    float e2 = b2f(hi.x), o2 = b2f(hi.y), e3 = b2f(hi.z), o3 = b2f(hi.w);
    ushort4 r0, r1;
    r0.x = f2bf(e0*cv.x - o0*sv.x); r0.y = f2bf(o0*cv.x + e0*sv.x);
    r0.z = f2bf(e1*cv.y - o1*sv.y); r0.w = f2bf(o1*cv.y + e1*sv.y);
    r1.x = f2bf(e2*cv.z - o2*sv.z); r1.y = f2bf(o2*cv.z + e2*sv.z);
    r1.z = f2bf(e3*cv.w - o3*sv.w); r1.w = f2bf(o3*cv.w + e3*sv.w);
    ((ushort4*)X)[idx*2]     = r0;
    ((ushort4*)X)[idx*2 + 1] = r1;
}

// ---------------- GEMM: C(8192 x N) = A(8192 x K) * BT(N x K)^T, bf16 in, fp32 acc --------
// MODE 0: bf16 out -> O0.  MODE 1: fp32 out -> O0.  MODE 2: split cols [0,2048)->O0, [2048,4096)->O1 (bf16)
template<int MODE>
__global__ void gemm_bt_k(const u16* __restrict__ A, const u16* __restrict__ BT,
                          void* __restrict__ O0, void* __restrict__ O1, int N, int K)
{
    __shared__ alignas(16) u16 As[128*64];
    __shared__ alignas(16) u16 Bs[128*64];
    const int tid  = threadIdx.x;
    const int wave = tid >> 6, lane = tid & 63;
    const int l15 = lane & 15, l4 = lane >> 4;
    const int wm = wave >> 1, wn = wave & 1;
    const size_t arow0 = (size_t)blockIdx.x * 128;
    const size_t brow0 = (size_t)blockIdx.y * 128;
    const u16* Ab = A  + arow0 * K;
    const u16* Bb = BT + brow0 * K;

    f32x4 acc[4][4] = {};

    for (int k0 = 0; k0 < K; k0 += 64) {
        // stage 128x64 bf16 tiles: 1024 x 16B chunks each; linear LDS dest,
        // inverse-swizzled global source (slot ^= row&7 within the 8-slot row)
        #pragma unroll
        for (int j = 0; j < 4; ++j) {
            int p = j*256 + wave*64 + lane;
            int row = p >> 3, slot = p & 7;
            int gs = slot ^ (row & 7);
            glds16(Ab + (size_t)row*K + k0 + gs*8, &As[(size_t)(j*256 + wave*64)*8]);
            glds16(Bb + (size_t)row*K + k0 + gs*8, &Bs[(size_t)(j*256 + wave*64)*8]);
        }
        __syncthreads();
        #pragma unroll
        for (int kk = 0; kk < 2; ++kk) {
            bf16x8 af[4], bfr[4];
            #pragma unroll
            for (int m = 0; m < 4; ++m) {
                int row = wm*64 + m*16 + l15;
                int byt = row*128 + (((kk*4 + l4)*16) ^ ((row & 7) << 4));
                af[m] = *(const bf16x8*)&As[byt >> 1];
            }
            #pragma unroll
            for (int n = 0; n < 4; ++n) {
                int row = wn*64 + n*16 + l15;
                int byt = row*128 + (((kk*4 + l4)*16) ^ ((row & 7) << 4));
                bfr[n] = *(const bf16x8*)&Bs[byt >> 1];
            }
            #pragma unroll
            for (int m = 0; m < 4; ++m)
                #pragma unroll
                for (int n = 0; n < 4; ++n)
                    acc[m][n] = __builtin_amdgcn_mfma_f32_16x16x32_bf16(af[m], bfr[n], acc[m][n], 0, 0, 0);
        }
        __syncthreads();
    }

    // epilogue: C/D layout col = lane&15, row = (lane>>4)*4 + j
    #pragma unroll
    for (int m = 0; m < 4; ++m)
      #pragma unroll
      for (int n = 0; n < 4; ++n)
        #pragma unroll
        for (int j = 0; j < 4; ++j) {
            size_t row = arow0 + wm*64 + m*16 + l4*4 + j;
            size_t col = brow0 + wn*64 + n*16 + l15;
            float v = acc[m][n][j];
            if (MODE == 0) {
                ((u16*)O0)[row * N + col] = f2bf(v);
            } else if (MODE == 1) {
                ((float*)O0)[row * N + col] = v;
            } else {
                if (col < 2048) ((u16*)O0)[row * 2048 + col]          = f2bf(v);
                else            ((u16*)O1)[row * 2048 + (col - 2048)] = f2bf(v);
            }
        }
}

// ---------------- causal flash attention ----------------
// grid (T/64, B*H); block 256 = 4 waves, each wave owns 16 q-rows.
// Q,K: (B,T,16*128) bf16 (post-RoPE). VT: (B,H,128,T) bf16. O: (B,T,16*128) bf16.
__global__ void attn_k(const u16* __restrict__ Q, const u16* __restrict__ Kg,
                       const u16* __restrict__ VT, u16* __restrict__ O)
{
    __shared__ alignas(16) u16 Ks[64*128];    // [key][d]   swizzled
    __shared__ alignas(16) u16 Vs[128*64];    // [d][key]   swizzled
    __shared__ alignas(16) u16 Ps[4][16*64];  // per-wave P tile [qrow][key] swizzled
    const int tid  = threadIdx.x;
    const int wave = tid >> 6, lane = tid & 63;
    const int l15 = lane & 15, l4 = lane >> 4;
    const int qt = blockIdx.x, bh = blockIdx.y;
    const int b = bh >> 4, h = bh & 15;
    const u16* qb  = Q  + ((size_t)b*2048)*2048 + h*128;
    const u16* kb_ = Kg + ((size_t)b*2048)*2048 + h*128;
    const u16* vtb = VT + (size_t)bh*128*2048;
    const int q0 = qt*64, wq0 = q0 + wave*16;

    bf16x8 qf[4];
    #pragma unroll
    for (int ds = 0; ds < 4; ++ds)
        qf[ds] = *(const bf16x8*)(qb + (size_t)(wq0 + l15)*2048 + ds*32 + l4*8);

    f32x4 oacc[8] = {};
    float mrow[4] = {-__builtin_inff(), -__builtin_inff(), -__builtin_inff(), -__builtin_inff()};
    float lrow[4] = {0.f, 0.f, 0.f, 0.f};

    for (int kb0 = 0; kb0 <= q0 + 63; kb0 += 64) {
        // stage K tile (64 rows x 256B = 16 chunks/row) and VT tile (128 rows x 128B = 8 chunks/row)
        #pragma unroll
        for (int j = 0; j < 4; ++j) {
            int p = j*256 + wave*64 + lane;
            { int row = p >> 4, slot = p & 15, gs = slot ^ (row & 7);
              glds16(kb_ + (size_t)(kb0 + row)*2048 + gs*8, &Ks[(size_t)(j*256 + wave*64)*8]); }
            { int row = p >> 3, slot = p & 7,  gs = slot ^ (row & 7);
              glds16(vtb + (size_t)row*2048 + kb0 + gs*8,   &Vs[(size_t)(j*256 + wave*64)*8]); }
        }
        __syncthreads();

        if (kb0 <= wq0 + 15) {          // wave has at least one valid key in this block
            // S = Q K^T  (4 key sub-tiles of 16)
            f32x4 s[4];
            #pragma unroll
            for (int n2 = 0; n2 < 4; ++n2) {
                f32x4 sa = {};
                #pragma unroll
                for (int ds = 0; ds < 4; ++ds) {
                    int row = n2*16 + l15;
                    int byt = row*256 + (((ds*4 + l4)*16) ^ ((row & 7) << 4));
                    bf16x8 kf = *(const bf16x8*)&Ks[byt >> 1];
                    sa = __builtin_amdgcn_mfma_f32_16x16x32_bf16(qf[ds], kf, sa, 0, 0, 0);
                }
                s[n2] = sa;
            }
            // scale + causal mask + online softmax (rows = l4*4+j, cols across 16 lanes)
            float mnew[4] = {mrow[0], mrow[1], mrow[2], mrow[3]};
            #pragma unroll
            for (int n2 = 0; n2 < 4; ++n2) {
                int key = kb0 + n2*16 + l15;
                #pragma unroll
                for (int j = 0; j < 4; ++j) {
                    int trow = wq0 + l4*4 + j;
                    float v = s[n2][j] * SM_SCALE;
                    v = (key <= trow) ? v : -__builtin_inff();
                    s[n2][j] = v;
                    mnew[j] = fmaxf(mnew[j], v);
                }
            }
            #pragma unroll
            for (int j = 0; j < 4; ++j) {
                float m_ = mnew[j];
                m_ = fmaxf(m_, __shfl_xor(m_, 1));
                m_ = fmaxf(m_, __shfl_xor(m_, 2));
                m_ = fmaxf(m_, __shfl_xor(m_, 4));
                m_ = fmaxf(m_, __shfl_xor(m_, 8));
                mnew[j] = m_;
            }
            float alpha[4], lad[4] = {0.f, 0.f, 0.f, 0.f};
            #pragma unroll
            for (int j = 0; j < 4; ++j) {
                alpha[j] = exp2f((mrow[j] - mnew[j]) * LOG2E);
                mrow[j] = mnew[j];
            }
            #pragma unroll
            for (int n2 = 0; n2 < 4; ++n2)
                #pragma unroll
                for (int j = 0; j < 4; ++j) {
                    float pv = exp2f((s[n2][j] - mrow[j]) * LOG2E);
                    s[n2][j] = pv;
                    lad[j] += pv;
                }
            #pragma unroll
            for (int j = 0; j < 4; ++j) {
                float t_ = lad[j];
                t_ += __shfl_xor(t_, 1);
                t_ += __shfl_xor(t_, 2);
                t_ += __shfl_xor(t_, 4);
                t_ += __shfl_xor(t_, 8);
                lrow[j] = lrow[j]*alpha[j] + t_;
            }
            #pragma unroll
            for (int n = 0; n < 8; ++n)
                #pragma unroll
                for (int j = 0; j < 4; ++j) oacc[n][j] *= alpha[j];

            // P (C-layout regs) -> LDS -> A-layout frags
            u16* pw = Ps[wave];
            #pragma unroll
            for (int n2 = 0; n2 < 4; ++n2)
                #pragma unroll
                for (int j = 0; j < 4; ++j) {
                    int row = l4*4 + j;
                    int col = n2*16 + l15;
                    int byt = row*128 + ((((col >> 3) << 4)) ^ ((row & 7) << 4)) + (col & 7)*2;
                    pw[byt >> 1] = f2bf(s[n2][j]);
                }
            bf16x8 pf[2];
            #pragma unroll
            for (int kst = 0; kst < 2; ++kst) {
                int row = l15;
                int byt = row*128 + (((kst*4 + l4)*16) ^ ((row & 7) << 4));
                pf[kst] = *(const bf16x8*)&pw[byt >> 1];
            }
            // O += P V
            #pragma unroll
            for (int kst = 0; kst < 2; ++kst)
                #pragma unroll
                for (int n = 0; n < 8; ++n) {
                    int d = n*16 + l15;
                    int byt = d*128 + (((kst*4 + l4)*16) ^ ((d & 7) << 4));
                    bf16x8 vf = *(const bf16x8*)&Vs[byt >> 1];
                    oacc[n] = __builtin_amdgcn_mfma_f32_16x16x32_bf16(pf[kst], vf, oacc[n], 0, 0, 0);
                }
        }
        __syncthreads();
    }

    float inv[4];
    #pragma unroll
    for (int j = 0; j < 4; ++j) inv[j] = 1.0f / lrow[j];
    #pragma unroll
    for (int n = 0; n < 8; ++n)
        #pragma unroll
        for (int j = 0; j < 4; ++j) {
            size_t t = (size_t)wq0 + l4*4 + j;
            O[((size_t)b*2048 + t)*2048 + h*128 + n*16 + l15] = f2bf(oacc[n][j] * inv[j]);
        }
}

extern "C" void kernel_launch(void* const* d_in, const int* in_sizes, int n_in,
                              void* d_out, int out_size, void* d_ws, size_t ws_size,
                              hipStream_t stream)
{
    const float* x    = (const float*)d_in[0];
    const float* cosT = (const float*)d_in[1];
    const float* sinT = (const float*)d_in[2];
    const float* Wq   = (const float*)d_in[3];
    const float* Wkd  = (const float*)d_in[4];
    const float* Wku  = (const float*)d_in[5];
    const float* Wo   = (const float*)d_in[6];
    float* out = (float*)d_out;

    // workspace layout (bf16 buffers); buf0 triple-duty: x_bf16 -> v -> attn_out
    char* p = (char*)d_ws;
    u16* buf0  = (u16*)p; p += (size_t)16777216*2;  // 8192x2048
    u16* WqT   = (u16*)p; p += (size_t) 4194304*2;  // 2048x2048
    u16* WkdT  = (u16*)p; p += (size_t) 1048576*2;  // 512x2048
    u16* WkuT  = (u16*)p; p += (size_t) 2097152*2;  // 4096x512
    u16* WoT   = (u16*)p; p += (size_t) 4194304*2;  // 2048x2048
    u16* qbuf  = (u16*)p; p += (size_t)16777216*2;  // 8192x2048
    u16* kbuf  = (u16*)p; p += (size_t)16777216*2;  // 8192x2048
    u16* vtb   = (u16*)p; p += (size_t)16777216*2;  // (B,H,128,T)
    u16* kvlat = (u16*)p; p += (size_t) 4194304*2;  // 8192x512

    cvt_bf16_k<<<4096, 256, 0, stream>>>(x, buf0, (size_t)4194304);

    transpose_w_k<<<dim3(  64, 64), 256, 0, stream>>>(Wq,  WqT,  2048, 2048);
    transpose_w_k<<<dim3(  16, 64), 256, 0, stream>>>(Wkd, WkdT, 2048,  512);
    transpose_w_k<<<dim3( 128, 16), 256, 0, stream>>>(Wku, WkuT,  512, 4096);
    transpose_w_k<<<dim3(  64, 64), 256, 0, stream>>>(Wo,  WoT,  2048, 2048);

    gemm_bt_k<0><<<dim3(64, 16), 256, 0, stream>>>(buf0,  WqT,  qbuf,  nullptr, 2048, 2048);
    gemm_bt_k<0><<<dim3(64,  4), 256, 0, stream>>>(buf0,  WkdT, kvlat, nullptr,  512, 2048);
    gemm_bt_k<2><<<dim3(64, 32), 256, 0, stream>>>(kvlat, WkuT, kbuf,  buf0,    4096,  512);

    rope_k<<<8192, 256, 0, stream>>>(qbuf, cosT, sinT);
    rope_k<<<8192, 256, 0, stream>>>(kbuf, cosT, sinT);

    transpose_v_k<<<dim3(64, 4, 64), 256, 0, stream>>>(buf0, vtb);

    attn_k<<<dim3(32, 64), 256, 0, stream>>>(qbuf, kbuf, vtb, buf0);

    gemm_bt_k<1><<<dim3(64, 16), 256, 0, stream>>>(buf0, WoT, out, nullptr, 2048, 2048);
}

// Round 2
// 553.690 us; speedup vs baseline: 1.3468x; 1.3468x over previous
//
#include <hip/hip_runtime.h>

typedef __bf16 bf16x8 __attribute__((ext_vector_type(8)));
typedef float  f32x4  __attribute__((ext_vector_type(4)));
typedef float  f32x16 __attribute__((ext_vector_type(16)));
typedef unsigned int u32;
typedef unsigned int u32x4 __attribute__((ext_vector_type(4)));
typedef unsigned short u16;

#define LOG2E    1.4426950408889634f
#define SM_SCALE 0.08838834764831845f   // 1/sqrt(128)

__device__ __forceinline__ u16 f2bf(float f) {
    unsigned int u = __builtin_bit_cast(unsigned int, f);
    u += 0x7fffu + ((u >> 16) & 1u);    // RNE
    return (u16)(u >> 16);
}
__device__ __forceinline__ float b2f(u16 h) {
    unsigned int u = ((unsigned int)h) << 16;
    return __builtin_bit_cast(float, u);
}
__device__ __forceinline__ void glds16(const void* g, void* l) {
    __builtin_amdgcn_global_load_lds(
        (__attribute__((address_space(1))) void*)g,
        (__attribute__((address_space(3))) void*)l, 16, 0, 0);
}

// ---------------- fp32 -> bf16 convert ----------------
__global__ void cvt_bf16_k(const float* __restrict__ in, u16* __restrict__ out, size_t n4) {
    size_t i = (size_t)blockIdx.x * blockDim.x + threadIdx.x;
    size_t stride = (size_t)gridDim.x * blockDim.x;
    for (; i < n4; i += stride) {
        float4 v = ((const float4*)in)[i];
        ushort4 r;
        r.x = f2bf(v.x); r.y = f2bf(v.y); r.z = f2bf(v.z); r.w = f2bf(v.w);
        ((ushort4*)out)[i] = r;
    }
}

// ---------------- W (K x N fp32) -> WT (N x K bf16) ----------------
__global__ void transpose_w_k(const float* __restrict__ W, u16* __restrict__ WT, int K, int N) {
    __shared__ float tile[32][33];
    int tx = threadIdx.x & 31, ty = threadIdx.x >> 5;
    int bx = blockIdx.x, by = blockIdx.y;
    #pragma unroll
    for (int i = 0; i < 4; ++i) {
        int r = by*32 + ty + i*8;
        tile[ty + i*8][tx] = W[(size_t)r * N + bx*32 + tx];
    }
    __syncthreads();
    #pragma unroll
    for (int i = 0; i < 4; ++i) {
        int n = bx*32 + ty + i*8;
        WT[(size_t)n * K + by*32 + tx] = f2bf(tile[tx][ty + i*8]);
    }
}

// ---------------- v (B,T,H*128) bf16 -> vt (B,H,128,T) bf16 ----------------
__global__ void transpose_v_k(const u16* __restrict__ V, u16* __restrict__ VT) {
    __shared__ u16 tile[32][33];
    int tx = threadIdx.x & 31, ty = threadIdx.x >> 5;
    int tT = blockIdx.x, tD = blockIdx.y, bh = blockIdx.z;
    int b = bh >> 4, h = bh & 15;
    #pragma unroll
    for (int i = 0; i < 4; ++i) {
        int t = tT*32 + ty + i*8;
        int d = tD*32 + tx;
        tile[ty + i*8][tx] = V[((size_t)(b*2048 + t))*2048 + h*128 + d];
    }
    __syncthreads();
    #pragma unroll
    for (int i = 0; i < 4; ++i) {
        int d = tD*32 + ty + i*8;
        int t = tT*32 + tx;
        VT[((size_t)bh*128 + d)*2048 + t] = tile[tx][ty + i*8];
    }
}

// ---------------- RoPE in-place on (B,T,16,128) bf16, optional output scale ----------------
__global__ void rope_k(u16* __restrict__ X, const float* __restrict__ C, const float* __restrict__ S,
                       float scale) {
    size_t idx = (size_t)blockIdx.x * blockDim.x + threadIdx.x;  // one thread = 4 pairs (8 elems)
    size_t pair0 = idx * 4;
    int i = (int)(pair0 & 63);
    size_t rem = pair0 >> 6;
    int t = (int)((rem >> 4) & 2047);
    float4 cv = *(const float4*)(C + (size_t)t*64 + i);
    float4 sv = *(const float4*)(S + (size_t)t*64 + i);
    ushort4 lo = ((const ushort4*)X)[idx*2];
    ushort4 hi = ((const ushort4*)X)[idx*2 + 1];
    float e0 = b2f(lo.x), o0 = b2f(lo.y), e1 = b2f(lo.z), o1 = b2f(lo.w);
    float e2 = b2f(hi.x), o2 = b2f(hi.y), e3 = b2f(hi.z), o3 = b2f(hi.w);
    ushort4 r0, r1;
    r0.x = f2bf((e0*cv.x - o0*sv.x)*scale); r0.y = f2bf((o0*cv.x + e0*sv.x)*scale);
    r0.z = f2bf((e1*cv.y - o1*sv.y)*scale); r0.w = f2bf((o1*cv.y + e1*sv.y)*scale);
    r1.x = f2bf((e2*cv.z - o2*sv.z)*scale); r1.y = f2bf((o2*cv.z + e2*sv.z)*scale);
    r1.z = f2bf((e3*cv.w - o3*sv.w)*scale); r1.w = f2bf((o3*cv.w + e3*sv.w)*scale);
    ((ushort4*)X)[idx*2]     = r0;
    ((ushort4*)X)[idx*2 + 1] = r1;
}

// ---------------- GEMM: C(8192 x N) = A(8192 x K) * BT(N x K)^T, bf16 in, fp32 acc --------
template<int MODE>
__global__ void gemm_bt_k(const u16* __restrict__ A, const u16* __restrict__ BT,
                          void* __restrict__ O0, void* __restrict__ O1, int N, int K)
{
    __shared__ alignas(16) u16 As[128*64];
    __shared__ alignas(16) u16 Bs[128*64];
    const int tid  = threadIdx.x;
    const int wave = tid >> 6, lane = tid & 63;
    const int l15 = lane & 15, l4 = lane >> 4;
    const int wm = wave >> 1, wn = wave & 1;
    const size_t arow0 = (size_t)blockIdx.x * 128;
    const size_t brow0 = (size_t)blockIdx.y * 128;
    const u16* Ab = A  + arow0 * K;
    const u16* Bb = BT + brow0 * K;

    f32x4 acc[4][4] = {};

    for (int k0 = 0; k0 < K; k0 += 64) {
        #pragma unroll
        for (int j = 0; j < 4; ++j) {
            int p = j*256 + wave*64 + lane;
            int row = p >> 3, slot = p & 7;
            int gs = slot ^ (row & 7);
            glds16(Ab + (size_t)row*K + k0 + gs*8, &As[(size_t)(j*256 + wave*64)*8]);
            glds16(Bb + (size_t)row*K + k0 + gs*8, &Bs[(size_t)(j*256 + wave*64)*8]);
        }
        __syncthreads();
        #pragma unroll
        for (int kk = 0; kk < 2; ++kk) {
            bf16x8 af[4], bfr[4];
            #pragma unroll
            for (int m = 0; m < 4; ++m) {
                int row = wm*64 + m*16 + l15;
                int byt = row*128 + (((kk*4 + l4)*16) ^ ((row & 7) << 4));
                af[m] = *(const bf16x8*)&As[byt >> 1];
            }
            #pragma unroll
            for (int n = 0; n < 4; ++n) {
                int row = wn*64 + n*16 + l15;
                int byt = row*128 + (((kk*4 + l4)*16) ^ ((row & 7) << 4));
                bfr[n] = *(const bf16x8*)&Bs[byt >> 1];
            }
            #pragma unroll
            for (int m = 0; m < 4; ++m)
                #pragma unroll
                for (int n = 0; n < 4; ++n)
                    acc[m][n] = __builtin_amdgcn_mfma_f32_16x16x32_bf16(af[m], bfr[n], acc[m][n], 0, 0, 0);
        }
        __syncthreads();
    }

    #pragma unroll
    for (int m = 0; m < 4; ++m)
      #pragma unroll
      for (int n = 0; n < 4; ++n)
        #pragma unroll
        for (int j = 0; j < 4; ++j) {
            size_t row = arow0 + wm*64 + m*16 + l4*4 + j;
            size_t col = brow0 + wn*64 + n*16 + l15;
            float v = acc[m][n][j];
            if (MODE == 0) {
                ((u16*)O0)[row * N + col] = f2bf(v);
            } else if (MODE == 1) {
                ((float*)O0)[row * N + col] = v;
            } else {
                if (col < 2048) ((u16*)O0)[row * 2048 + col]          = f2bf(v);
                else            ((u16*)O1)[row * 2048 + (col - 2048)] = f2bf(v);
            }
        }
}

// ---------------- causal flash attention, swapped-QK^T 32x32 MFMA ----------------
// grid (16, 64): qt in [0,16) (128 q rows each), bh in [0,64). block 256 = 4 waves x 32 q rows.
// Q prescaled by SM_SCALE*LOG2E. Q,K: (B,T,2048) bf16; VT: (B,H,128,T) bf16; O: (B,T,2048) bf16.
__global__ __launch_bounds__(256, 2) void attn_k(const u16* __restrict__ Qg, const u16* __restrict__ Kg,
                       const u16* __restrict__ VTg, u16* __restrict__ Og)
{
    __shared__ alignas(16) u16 Ks[2][64*128];   // [key][d], 256B rows, 16B chunks swz ^(row&7)
    __shared__ alignas(16) u16 Vs[2][128*64];   // [d][key], 128B rows, 16B chunks swz ^(row&7)
    const int tid = threadIdx.x, wave = tid >> 6, lane = tid & 63;
    const int l31 = lane & 31, hi = lane >> 5;

    // XCD-chunked remap (1024 blocks, 8 XCDs) + longest-first qt
    int flat = blockIdx.x + 16*blockIdx.y;
    int nf = (flat & 7)*128 + (flat >> 3);
    const int qt = 15 - (nf & 15), bh = nf >> 4;
    const int b = bh >> 4, h = bh & 15;
    const u16* kb_ = Kg  + ((size_t)b*2048)*2048 + h*128;
    const u16* vtb = VTg + (size_t)bh*128*2048;
    const int q0 = qt*128, wq0 = q0 + wave*32, qv = wq0 + l31;

    // Q fragments in registers: lane holds Q[qv][kst*16 + hi*8 + 0..7]
    bf16x8 qf[8];
    {
        const u16* qb = Qg + ((size_t)(b*2048 + qv))*2048 + h*128;
        #pragma unroll
        for (int kst = 0; kst < 8; ++kst)
            qf[kst] = *(const bf16x8*)(qb + kst*16 + hi*8);
    }

    f32x16 oacc[4] = {};                 // O^T: [dtile], C-layout col=q(l31), row=d
    float mrun = -__builtin_inff(), lrun = 0.f;

    auto STAGE = [&](int bi, int kb) {
        #pragma unroll
        for (int j = 0; j < 4; ++j) {
            int p = j*256 + wave*64 + lane;
            { int row = p >> 4, slot = p & 15, gs = slot ^ (row & 7);
              glds16(kb_ + (size_t)(kb + row)*2048 + gs*8, &Ks[bi][(j*256 + wave*64)*8]); }
            { int row = p >> 3, slot = p & 7,  gs = slot ^ (row & 7);
              glds16(vtb + (size_t)row*2048 + kb + gs*8,   &Vs[bi][(j*256 + wave*64)*8]); }
        }
    };

    const int NT = 2*qt + 2;             // number of 64-key blocks
    STAGE(0, 0);
    __syncthreads();

    for (int it = 0; it < NT; ++it) {
        const int cur = it & 1;
        const int kb0 = it * 64;
        if (it + 1 < NT) STAGE(cur ^ 1, (it + 1) * 64);

        if (kb0 <= wq0 + 31) {
            // S^T = K Q^T : two 32-key tiles, lane&31 = q
            f32x16 s[2];
            #pragma unroll
            for (int t = 0; t < 2; ++t) {
                f32x16 sa = {};
                #pragma unroll
                for (int kst = 0; kst < 8; ++kst) {
                    int row = t*32 + l31;
                    int ch = (kst*2 + hi) ^ (row & 7);
                    bf16x8 kf = *(const bf16x8*)&Ks[cur][row*128 + ch*8];
                    sa = __builtin_amdgcn_mfma_f32_32x32x16_bf16(kf, qf[kst], sa, 0, 0, 0);
                }
                s[t] = sa;
            }
            // causal mask (diagonal wave-blocks only)
            if (kb0 + 63 > wq0) {
                #pragma unroll
                for (int t = 0; t < 2; ++t)
                    #pragma unroll
                    for (int r = 0; r < 16; ++r) {
                        int key = kb0 + t*32 + (r & 3) + 8*(r >> 2) + 4*hi;
                        if (key > qv) s[t][r] = -__builtin_inff();
                    }
            }
            // row max: 31 in-lane + 1 cross-half
            float pm = s[0][0];
            #pragma unroll
            for (int r = 1; r < 16; ++r) pm = fmaxf(pm, s[0][r]);
            #pragma unroll
            for (int r = 0; r < 16; ++r) pm = fmaxf(pm, s[1][r]);
            pm = fmaxf(pm, __shfl_xor(pm, 32));
            // defer-max rescale (T13, THR=8 in log2 units)
            if (!__all(pm <= mrun + 8.0f)) {
                float mnew = fmaxf(mrun, pm);
                float alpha = exp2f(mrun - mnew);
                mrun = mnew;
                lrun *= alpha;
                #pragma unroll
                for (int dt = 0; dt < 4; ++dt)
                    #pragma unroll
                    for (int r = 0; r < 16; ++r) oacc[dt][r] *= alpha;
            }
            // p = 2^(s - m), row sum
            float sum = 0.f;
            #pragma unroll
            for (int t = 0; t < 2; ++t)
                #pragma unroll
                for (int r = 0; r < 16; ++r) {
                    float p = exp2f(s[t][r] - mrun);
                    s[t][r] = p;
                    sum += p;
                }
            sum += __shfl_xor(sum, 32);
            lrun += sum;
            // pack P to bf16 pairs: P2[t][g][i] = keys (t*32+8g+4hi+2i, +1) for q=l31
            u32 P2[2][4][2];
            #pragma unroll
            for (int t = 0; t < 2; ++t)
                #pragma unroll
                for (int g = 0; g < 4; ++g)
                    #pragma unroll
                    for (int i = 0; i < 2; ++i)
                        asm("v_cvt_pk_bf16_f32 %0, %1, %2"
                            : "=v"(P2[t][g][i])
                            : "v"(s[t][g*4 + 2*i]), "v"(s[t][g*4 + 2*i + 1]));
            // O^T += V^T P^T : build P B-frags via half-lane exchange
            #pragma unroll
            for (int kst = 0; kst < 4; ++kst) {
                const int t = kst >> 1, bg = (kst & 1)*2;
                u32 own0 = hi ? P2[t][bg+1][0] : P2[t][bg][0];
                u32 own1 = hi ? P2[t][bg+1][1] : P2[t][bg][1];
                u32 snd0 = hi ? P2[t][bg][0]   : P2[t][bg+1][0];
                u32 snd1 = hi ? P2[t][bg][1]   : P2[t][bg+1][1];
                u32 rcv0 = (u32)__shfl_xor((int)snd0, 32);
                u32 rcv1 = (u32)__shfl_xor((int)snd1, 32);
                u32x4 wv;
                wv.x = hi ? rcv0 : own0;
                wv.y = hi ? rcv1 : own1;
                wv.z = hi ? own0 : rcv0;
                wv.w = hi ? own1 : rcv1;
                bf16x8 pf = __builtin_bit_cast(bf16x8, wv);
                #pragma unroll
                for (int dt = 0; dt < 4; ++dt) {
                    int row = dt*32 + l31;
                    int ch = (kst*2 + hi) ^ (row & 7);
                    bf16x8 vf = *(const bf16x8*)&Vs[cur][row*64 + ch*8];
                    oacc[dt] = __builtin_amdgcn_mfma_f32_32x32x16_bf16(vf, pf, oacc[dt], 0, 0, 0);
                }
            }
        }
        __syncthreads();
    }

    // epilogue: O^T regs -> O[b, t=qv, h, d], d = dt*32 + 8*rg + 4*hi + j
    float inv = 1.0f / lrun;
    u16* ob = Og + ((size_t)(b*2048 + qv))*2048 + h*128;
    #pragma unroll
    for (int dt = 0; dt < 4; ++dt)
        #pragma unroll
        for (int rg = 0; rg < 4; ++rg) {
            float a0 = oacc[dt][rg*4+0]*inv, a1 = oacc[dt][rg*4+1]*inv;
            float a2 = oacc[dt][rg*4+2]*inv, a3 = oacc[dt][rg*4+3]*inv;
            u32 wA, wB;
            asm("v_cvt_pk_bf16_f32 %0, %1, %2" : "=v"(wA) : "v"(a0), "v"(a1));
            asm("v_cvt_pk_bf16_f32 %0, %1, %2" : "=v"(wB) : "v"(a2), "v"(a3));
            int dbase = dt*32 + rg*8 + hi*4;
            *(u32*)(ob + dbase)     = wA;
            *(u32*)(ob + dbase + 2) = wB;
        }
}

extern "C" void kernel_launch(void* const* d_in, const int* in_sizes, int n_in,
                              void* d_out, int out_size, void* d_ws, size_t ws_size,
                              hipStream_t stream)
{
    const float* x    = (const float*)d_in[0];
    const float* cosT = (const float*)d_in[1];
    const float* sinT = (const float*)d_in[2];
    const float* Wq   = (const float*)d_in[3];
    const float* Wkd  = (const float*)d_in[4];
    const float* Wku  = (const float*)d_in[5];
    const float* Wo   = (const float*)d_in[6];
    float* out = (float*)d_out;

    char* p = (char*)d_ws;
    u16* buf0  = (u16*)p; p += (size_t)16777216*2;  // 8192x2048
    u16* WqT   = (u16*)p; p += (size_t) 4194304*2;
    u16* WkdT  = (u16*)p; p += (size_t) 1048576*2;
    u16* WkuT  = (u16*)p; p += (size_t) 2097152*2;
    u16* WoT   = (u16*)p; p += (size_t) 4194304*2;
    u16* qbuf  = (u16*)p; p += (size_t)16777216*2;
    u16* kbuf  = (u16*)p; p += (size_t)16777216*2;
    u16* vtb   = (u16*)p; p += (size_t)16777216*2;
    u16* kvlat = (u16*)p; p += (size_t) 4194304*2;

    cvt_bf16_k<<<4096, 256, 0, stream>>>(x, buf0, (size_t)4194304);

    transpose_w_k<<<dim3(  64, 64), 256, 0, stream>>>(Wq,  WqT,  2048, 2048);
    transpose_w_k<<<dim3(  16, 64), 256, 0, stream>>>(Wkd, WkdT, 2048,  512);
    transpose_w_k<<<dim3( 128, 16), 256, 0, stream>>>(Wku, WkuT,  512, 4096);
    transpose_w_k<<<dim3(  64, 64), 256, 0, stream>>>(Wo,  WoT,  2048, 2048);

    gemm_bt_k<0><<<dim3(64, 16), 256, 0, stream>>>(buf0,  WqT,  qbuf,  nullptr, 2048, 2048);
    gemm_bt_k<0><<<dim3(64,  4), 256, 0, stream>>>(buf0,  WkdT, kvlat, nullptr,  512, 2048);
    gemm_bt_k<2><<<dim3(64, 32), 256, 0, stream>>>(kvlat, WkuT, kbuf,  buf0,    4096,  512);

    rope_k<<<8192, 256, 0, stream>>>(qbuf, cosT, sinT, SM_SCALE * LOG2E);  // fold softmax scale into Q
    rope_k<<<8192, 256, 0, stream>>>(kbuf, cosT, sinT, 1.0f);

    transpose_v_k<<<dim3(64, 4, 64), 256, 0, stream>>>(buf0, vtb);

    attn_k<<<dim3(16, 64), 256, 0, stream>>>(qbuf, kbuf, vtb, buf0);

    gemm_bt_k<1><<<dim3(64, 16), 256, 0, stream>>>(buf0, WoT, out, nullptr, 2048, 2048);
}